// Round 7
// baseline (202.723 us; speedup 1.0000x reference)
//
#include <hip/hip_runtime.h>
#include <hip/hip_bf16.h>

// BertSelfAttention on MI355X (gfx950). B=2, S=2048, H=1024, heads=16, dh=64.
// Inputs/output float32 (established round 2). Internal compute bf16 MFMA.
//
// Round 7: revert round-6 KV-split (regressed: halved MFMA-per-barrier and
// doubled total staging). Back to round-5 structure (block = 128 q x 8 waves,
// full KV sweep), but stage 256 kv per barrier-pair and run 4 compute subs
// (scores-64 -> PV-64) between barriers: barrier events 32 -> 16 per block,
// per-wave MFMA per pair 36 -> 72, staging bytes/kv unchanged. LDS = 80KB
// exactly -> 2 blocks/CU (= grid's 2 blocks/CU, same as round 5's ceiling).
// GEMM: bias now enters as MFMA C-initializer (epilogue adds deleted).

typedef __bf16 bf16x8 __attribute__((ext_vector_type(8)));
typedef __bf16 bf16x4 __attribute__((ext_vector_type(4)));
typedef float f32x4 __attribute__((ext_vector_type(4)));

static constexpr int H = 1024;
static constexpr int S = 2048;
static constexpr int NH = 16;
static constexpr int DH = 64;
static constexpr float L2E = 1.4426950408889634f;

#if __has_builtin(__builtin_amdgcn_exp2f)
#define EXP2F(x) __builtin_amdgcn_exp2f(x)
#else
#define EXP2F(x) __builtin_exp2f(x)
#endif

__device__ inline void gll16(const void* g, void* l) {
  __builtin_amdgcn_global_load_lds(
      (const __attribute__((address_space(1))) void*)g,
      (__attribute__((address_space(3))) void*)l, 16, 0, 0);
}

// Fused converts: blocks [0,2048) convert X f32->bf16; blocks [2048,2816)
// transpose-convert Wq/Wk/Wv -> Wt bf16 [n][k] via padded-LDS 64x64 tiles.
__global__ __launch_bounds__(256) void convert_kernel(
    const float* __restrict__ X, const float* __restrict__ W0,
    const float* __restrict__ W1, const float* __restrict__ W2,
    __bf16* __restrict__ Xb, __bf16* __restrict__ Wt) {
  __shared__ float T[64][65];
  const int bid = blockIdx.x, tid = threadIdx.x;
  if (bid < 2048) {
    size_t i = ((size_t)bid * 256 + tid) * 8;
    float4 f0 = *(const float4*)(X + i);
    float4 f1 = *(const float4*)(X + i + 4);
    bf16x8 o;
    o[0] = (__bf16)f0.x; o[1] = (__bf16)f0.y; o[2] = (__bf16)f0.z; o[3] = (__bf16)f0.w;
    o[4] = (__bf16)f1.x; o[5] = (__bf16)f1.y; o[6] = (__bf16)f1.z; o[7] = (__bf16)f1.w;
    *(bf16x8*)(Xb + i) = o;
    return;
  }
  const int wid = bid - 2048;
  const int z = wid >> 8, t = wid & 255;
  const int k0 = (t >> 4) * 64, n0 = (t & 15) * 64;
  const float* W = z == 0 ? W0 : (z == 1 ? W1 : W2);
  __bf16* Wo = Wt + (size_t)z * H * H;
#pragma unroll
  for (int it = 0; it < 4; ++it) {
    int r = it * 16 + (tid >> 4), c = (tid & 15) * 4;
    *(float4*)&T[r][c] = *(const float4*)&W[(size_t)(k0 + r) * H + n0 + c];
  }
  __syncthreads();
#pragma unroll
  for (int it = 0; it < 4; ++it) {
    int n = it * 16 + (tid >> 4), c0 = (tid & 15) * 4;
    bf16x4 o;
#pragma unroll
    for (int j = 0; j < 4; ++j) o[j] = (__bf16)T[c0 + j][n];
    *(bf16x4*)&Wo[(size_t)(n0 + n) * H + k0 + c0] = o;
  }
}

// Fused QKV GEMM: grid (24, 32). blockIdx.x: [0..7]=Q, [8..15]=K, [16..23]=V.
// 128x128 tile, BK=64. Bias enters as MFMA C-init. Q out [bh][d][s] (scaled
// 0.125*L2E), K out [bh][s][d], V out [bh][d][s].
__global__ __launch_bounds__(256, 3) void qkv_gemm_kernel(
    const __bf16* __restrict__ Xb, const __bf16* __restrict__ Wt,
    const float* __restrict__ bq, const float* __restrict__ bk,
    const float* __restrict__ bv,
    __bf16* __restrict__ Qt, __bf16* __restrict__ K, __bf16* __restrict__ Vt)
{
  __shared__ __bf16 As[128 * 64];   // [m][k], 8 chunks/row, XOR-swizzled
  __shared__ __bf16 Bs[128 * 64];   // [n][k], same

  const int tid = threadIdx.x, lane = tid & 63, w = tid >> 6;
  const int quad = lane >> 4, l16 = lane & 15;
  const int wsel = blockIdx.x >> 3;
  const int n0 = (blockIdx.x & 7) * 128;
  const int m0 = blockIdx.y * 128;
  const int wr = w & 1, wc = w >> 1;

  const __bf16* Wsel = Wt + (size_t)wsel * H * H;
  const float* bias = wsel == 0 ? bq : (wsel == 1 ? bk : bv);

  const __bf16* aptr[4];
  const __bf16* bptr[4];
#pragma unroll
  for (int i = 0; i < 4; ++i) {
    int s = w * 256 + i * 64 + lane;
    int row = s >> 3, col = s & 7, sc = col ^ (row & 7);
    aptr[i] = Xb + (size_t)(m0 + row) * H + sc * 8;
    bptr[i] = Wsel + (size_t)(n0 + row) * H + sc * 8;
  }

  // bias -> C-init (bias is along n; broadcast over rows)
  f32x4 acc[4][4];
#pragma unroll
  for (int u = 0; u < 4; ++u) {
    float bv_ = bias[n0 + wc * 64 + u * 16 + l16];
#pragma unroll
    for (int t = 0; t < 4; ++t) acc[t][u] = {bv_, bv_, bv_, bv_};
  }

  for (int k0 = 0; k0 < H; k0 += 64) {
    __syncthreads();
#pragma unroll
    for (int i = 0; i < 4; ++i) {
      gll16(aptr[i] + k0, &As[(w * 256 + i * 64) * 8]);
      gll16(bptr[i] + k0, &Bs[(w * 256 + i * 64) * 8]);
    }
    __syncthreads();
#pragma unroll
    for (int kc = 0; kc < 2; ++kc) {
      bf16x8 af[4], bfr[4];
#pragma unroll
      for (int t = 0; t < 4; ++t) {
        int ra = wr * 64 + t * 16 + l16;
        af[t] = *(const bf16x8*)&As[ra * 64 + (((kc * 4 + quad) ^ (ra & 7)) * 8)];
        int rb = wc * 64 + t * 16 + l16;
        bfr[t] = *(const bf16x8*)&Bs[rb * 64 + (((kc * 4 + quad) ^ (rb & 7)) * 8)];
      }
#pragma unroll
      for (int t = 0; t < 4; ++t)
#pragma unroll
        for (int u = 0; u < 4; ++u)
          acc[t][u] = __builtin_amdgcn_mfma_f32_16x16x32_bf16(af[t], bfr[u], acc[t][u], 0, 0, 0);
    }
  }

  const float qscale = 0.125f * L2E;
#pragma unroll
  for (int u = 0; u < 4; ++u) {
    int n = n0 + wc * 64 + u * 16 + l16;
    int head = n >> 6, d = n & 63;
#pragma unroll
    for (int t = 0; t < 4; ++t) {
      int srow = m0 + wr * 64 + t * 16 + quad * 4;
      int b = srow >> 11, si = srow & (S - 1);
      int bh = b * NH + head;
      if (wsel == 1) {
        __bf16* dst = K + ((size_t)bh * S + si) * DH + d;
#pragma unroll
        for (int r = 0; r < 4; ++r)
          dst[(size_t)r * DH] = (__bf16)acc[t][u][r];
      } else {
        float scl = wsel == 0 ? qscale : 1.0f;
        __bf16* outp = wsel == 0 ? Qt : Vt;
        bf16x4 o;
#pragma unroll
        for (int r = 0; r < 4; ++r) o[r] = (__bf16)(acc[t][u][r] * scl);
        *(bf16x4*)&outp[((size_t)bh * DH + d) * S + si] = o;
      }
    }
  }
}

// Flash attention, transposed scores, fixed-max softmax.
// grid (16, 32), 512 threads (8 waves), block = 128 q. Stage 256 kv per
// barrier-pair (8 pairs); 4 compute subs of [scores-64 -> PV-64] each.
__global__ __launch_bounds__(512, 4) void attn_kernel(
    const __bf16* __restrict__ Qt, const __bf16* __restrict__ K,
    const __bf16* __restrict__ Vt, const float* __restrict__ mask,
    float* __restrict__ out)
{
  __shared__ __align__(16) __bf16 Ks[256 * 64];   // [kv][d] 8 ch/row, 32KB
  __shared__ __align__(16) __bf16 Vs[64 * 256];   // [d][kv] 32 ch/row, 32KB
  __shared__ __align__(16) __bf16 Pb[8 * 16 * 64];// per-wave P[q][kv64], 16KB

  const int tid = threadIdx.x, lane = tid & 63, w = tid >> 6;  // w: 0..7
  const int quad = lane >> 4, l16 = lane & 15;
  const int bh = blockIdx.y, b = bh >> 4, h = bh & 15;
  const int q0 = blockIdx.x * 128;

  const __bf16* Qb = Qt + (size_t)bh * DH * S;   // [d][s]
  const __bf16* Kb = K + (size_t)bh * S * DH;    // [s][d]
  const __bf16* Vb = Vt + (size_t)bh * DH * S;   // [d][s]
  const float* mb = mask + (size_t)b * S;

  // Q B-fragments for this wave's 16 q columns (Q pre-scaled 0.125*log2e)
  const int q = q0 + w * 16 + l16;
  bf16x8 qf[2];
#pragma unroll
  for (int kc = 0; kc < 2; ++kc)
#pragma unroll
    for (int j = 0; j < 8; ++j)
      qf[kc][j] = Qb[(size_t)(kc * 32 + quad * 8 + j) * S + q];

  // ones A-fragment (row m=0) for the denominator MFMA
  bf16x8 ones_frag;
#pragma unroll
  for (int j = 0; j < 8; ++j) ones_frag[j] = (l16 == 0) ? (__bf16)1.0f : (__bf16)0.0f;

  // staging pointers: thread stages chunks s = i*512 + tid, i=0..3, for both
  // K (rows of 8 chunks, key row&7) and V (rows of 32 chunks, key row&31).
  const __bf16* kp[4];
  const __bf16* vp[4];
#pragma unroll
  for (int i = 0; i < 4; ++i) {
    int s = i * 512 + tid;
    int rk = s >> 3, ck = s & 7;
    kp[i] = Kb + (size_t)rk * DH + ((ck ^ (rk & 7)) * 8);
    int rv = s >> 5, cv = s & 31;
    vp[i] = Vb + (size_t)rv * S + ((cv ^ (rv & 31)) * 8);
  }

  f32x4 o[4] = {};
  f32x4 o4 = {};   // denominator (row 0 of ones-MFMA)

  const int key = l16 & 7;

  for (int pair = 0; pair < 8; ++pair) {
    __syncthreads();
    const size_t koff = (size_t)pair * 256 * DH;
    const int voff = pair * 256;
#pragma unroll
    for (int i = 0; i < 4; ++i) {
      gll16(kp[i] + koff, &Ks[(i * 512 + w * 64) * 8]);
      gll16(vp[i] + voff, &Vs[(i * 512 + w * 64) * 8]);
    }
    __syncthreads();

#pragma unroll
    for (int sub = 0; sub < 4; ++sub) {
      const int kvb = pair * 256 + sub * 64;
      // scores S^T (log2 domain), C-init = mask*log2e; P=exp2 -> per-wave LDS
#pragma unroll
      for (int t = 0; t < 4; ++t) {
        int rk = sub * 64 + t * 16 + l16;
        bf16x8 k0f = *(const bf16x8*)&Ks[(rk * 8 + (quad ^ key)) * 8];
        bf16x8 k1f = *(const bf16x8*)&Ks[(rk * 8 + ((4 + quad) ^ key)) * 8];
        float4 mv = *(const float4*)&mb[kvb + t * 16 + quad * 4];
        f32x4 z = {mv.x * L2E, mv.y * L2E, mv.z * L2E, mv.w * L2E};
        z = __builtin_amdgcn_mfma_f32_16x16x32_bf16(k0f, qf[0], z, 0, 0, 0);
        f32x4 sc = __builtin_amdgcn_mfma_f32_16x16x32_bf16(k1f, qf[1], z, 0, 0, 0);
        bf16x4 pk;
#pragma unroll
        for (int r = 0; r < 4; ++r) pk[r] = (__bf16)EXP2F(sc[r]);
        int c3 = 2 * t + (quad >> 1);
        *(bf16x4*)&Pb[(w * 16 + l16) * 64 + ((c3 ^ key) * 8 + (quad & 1) * 4)] = pk;
      }
      // O^T += V^T P^T ; ones-row MFMA accumulates denominator
#pragma unroll
      for (int tt = 0; tt < 2; ++tt) {
        bf16x8 pf = *(const bf16x8*)&Pb[(w * 16 + l16) * 64 + (((tt * 4 + quad) ^ key) * 8)];
#pragma unroll
        for (int u = 0; u < 4; ++u) {
          int d = u * 16 + l16;
          int c = sub * 8 + tt * 4 + quad;
          bf16x8 vf = *(const bf16x8*)&Vs[(d * 32 + (c ^ (d & 31))) * 8];
          o[u] = __builtin_amdgcn_mfma_f32_16x16x32_bf16(vf, pf, o[u], 0, 0, 0);
        }
        o4 = __builtin_amdgcn_mfma_f32_16x16x32_bf16(ones_frag, pf, o4, 0, 0, 0);
      }
    }
  }

  // denominator for q-col l16 sits on lane l16 (quad 0), reg 0
  float l_q = __shfl(o4[0], l16, 64);
  float invl = 1.0f / l_q;
#pragma unroll
  for (int u = 0; u < 4; ++u) {
    float4 st = {o[u][0] * invl, o[u][1] * invl, o[u][2] * invl, o[u][3] * invl};
    *(float4*)&out[((size_t)b * S + q) * H + h * DH + u * 16 + quad * 4] = st;
  }
}

extern "C" void kernel_launch(void* const* d_in, const int* in_sizes, int n_in,
                              void* d_out, int out_size, void* d_ws, size_t ws_size,
                              hipStream_t stream) {
  const float* X    = (const float*)d_in[0];
  const float* mask = (const float*)d_in[1];
  const float* Wq   = (const float*)d_in[2];
  const float* bq   = (const float*)d_in[3];
  const float* Wk   = (const float*)d_in[4];
  const float* bk   = (const float*)d_in[5];
  const float* Wv   = (const float*)d_in[6];
  const float* bv   = (const float*)d_in[7];
  float* out = (float*)d_out;

  const size_t per = (size_t)2 * NH * S * DH;   // 4M elems
  __bf16* Qws  = (__bf16*)d_ws;                 // 8MB  [bh][d][s]
  __bf16* Kws  = Qws + per;                     // 8MB  [bh][s][d]
  __bf16* Vtws = Kws + per;                     // 8MB  [bh][d][s]

  // GEMM-phase scratch inside d_out (16MB); attn overwrites all of d_out.
  __bf16* Xb = (__bf16*)d_out;                  // 8MB
  __bf16* Wt = Xb + per;                        // 3 x 2MB

  convert_kernel<<<2816, 256, 0, stream>>>(X, Wq, Wk, Wv, Xb, Wt);
  qkv_gemm_kernel<<<dim3(24, 32), 256, 0, stream>>>(Xb, Wt, bq, bk, bv,
                                                    Qws, Kws, Vtws);
  attn_kernel<<<dim3(16, 32), 512, 0, stream>>>(Qws, Kws, Vtws, mask, out);
}

// Round 8
// 170.345 us; speedup vs baseline: 1.1901x; 1.1901x over previous
//
#include <hip/hip_runtime.h>
#include <hip/hip_bf16.h>

// BertSelfAttention on MI355X (gfx950). B=2, S=2048, H=1024, heads=16, dh=64.
// Inputs/output float32 (established round 2). Internal compute bf16 MFMA.
//
// Round 8: r5-exact attention restored (kv-128 staging measured optimal:
// r6 kv-64 = 79us, r5 kv-128 = 54.5us, r7 kv-256 = 88us). GEMM epilogue
// rebuilt: Q and K accumulators bounce through dead staging LDS (per-wave
// 64x64 swizzled transpose) and store as 8x dwordx4 per lane instead of
// 64 scalar 2B (K) / 16x 8B strided (Q) stores. Q layout now [bh][s][d],
// which also vectorizes attn's Q-fragment loads (2x bf16x8).

typedef __bf16 bf16x8 __attribute__((ext_vector_type(8)));
typedef __bf16 bf16x4 __attribute__((ext_vector_type(4)));
typedef float f32x4 __attribute__((ext_vector_type(4)));

static constexpr int H = 1024;
static constexpr int S = 2048;
static constexpr int NH = 16;
static constexpr int DH = 64;
static constexpr float L2E = 1.4426950408889634f;

#if __has_builtin(__builtin_amdgcn_exp2f)
#define EXP2F(x) __builtin_amdgcn_exp2f(x)
#else
#define EXP2F(x) __builtin_exp2f(x)
#endif

__device__ inline void gll16(const void* g, void* l) {
  __builtin_amdgcn_global_load_lds(
      (const __attribute__((address_space(1))) void*)g,
      (__attribute__((address_space(3))) void*)l, 16, 0, 0);
}

// Fused converts: blocks [0,2048) convert X f32->bf16; blocks [2048,2816)
// transpose-convert Wq/Wk/Wv -> Wt bf16 [n][k] via padded-LDS 64x64 tiles.
__global__ __launch_bounds__(256) void convert_kernel(
    const float* __restrict__ X, const float* __restrict__ W0,
    const float* __restrict__ W1, const float* __restrict__ W2,
    __bf16* __restrict__ Xb, __bf16* __restrict__ Wt) {
  __shared__ float T[64][65];
  const int bid = blockIdx.x, tid = threadIdx.x;
  if (bid < 2048) {
    size_t i = ((size_t)bid * 256 + tid) * 8;
    float4 f0 = *(const float4*)(X + i);
    float4 f1 = *(const float4*)(X + i + 4);
    bf16x8 o;
    o[0] = (__bf16)f0.x; o[1] = (__bf16)f0.y; o[2] = (__bf16)f0.z; o[3] = (__bf16)f0.w;
    o[4] = (__bf16)f1.x; o[5] = (__bf16)f1.y; o[6] = (__bf16)f1.z; o[7] = (__bf16)f1.w;
    *(bf16x8*)(Xb + i) = o;
    return;
  }
  const int wid = bid - 2048;
  const int z = wid >> 8, t = wid & 255;
  const int k0 = (t >> 4) * 64, n0 = (t & 15) * 64;
  const float* W = z == 0 ? W0 : (z == 1 ? W1 : W2);
  __bf16* Wo = Wt + (size_t)z * H * H;
#pragma unroll
  for (int it = 0; it < 4; ++it) {
    int r = it * 16 + (tid >> 4), c = (tid & 15) * 4;
    *(float4*)&T[r][c] = *(const float4*)&W[(size_t)(k0 + r) * H + n0 + c];
  }
  __syncthreads();
#pragma unroll
  for (int it = 0; it < 4; ++it) {
    int n = it * 16 + (tid >> 4), c0 = (tid & 15) * 4;
    bf16x4 o;
#pragma unroll
    for (int j = 0; j < 4; ++j) o[j] = (__bf16)T[c0 + j][n];
    *(bf16x4*)&Wo[(size_t)(n0 + n) * H + k0 + c0] = o;
  }
}

// Fused QKV GEMM: grid (24, 32). blockIdx.x: [0..7]=Q, [8..15]=K, [16..23]=V.
// 128x128 tile, BK=64, bias as MFMA C-init. Q out [bh][s][d] (scaled
// 0.125*L2E), K out [bh][s][d] — both via LDS-bounce transpose + dwordx4
// stores. V out [bh][d][s] via bf16x4 strided stores.
__global__ __launch_bounds__(256, 3) void qkv_gemm_kernel(
    const __bf16* __restrict__ Xb, const __bf16* __restrict__ Wt,
    const float* __restrict__ bq, const float* __restrict__ bk,
    const float* __restrict__ bv,
    __bf16* __restrict__ Q, __bf16* __restrict__ K, __bf16* __restrict__ Vt)
{
  __shared__ __bf16 smem[2 * 128 * 64];   // As | Bs (32KB); reused as 4x64x64
  __bf16* As = smem;
  __bf16* Bs = smem + 128 * 64;

  const int tid = threadIdx.x, lane = tid & 63, w = tid >> 6;
  const int quad = lane >> 4, l16 = lane & 15;
  const int wsel = blockIdx.x >> 3;
  const int n0 = (blockIdx.x & 7) * 128;
  const int m0 = blockIdx.y * 128;
  const int wr = w & 1, wc = w >> 1;

  const __bf16* Wsel = Wt + (size_t)wsel * H * H;
  const float* bias = wsel == 0 ? bq : (wsel == 1 ? bk : bv);

  const __bf16* aptr[4];
  const __bf16* bptr[4];
#pragma unroll
  for (int i = 0; i < 4; ++i) {
    int s = w * 256 + i * 64 + lane;
    int row = s >> 3, col = s & 7, sc = col ^ (row & 7);
    aptr[i] = Xb + (size_t)(m0 + row) * H + sc * 8;
    bptr[i] = Wsel + (size_t)(n0 + row) * H + sc * 8;
  }

  // bias -> C-init (bias along n, broadcast over rows)
  f32x4 acc[4][4];
#pragma unroll
  for (int u = 0; u < 4; ++u) {
    float bv_ = bias[n0 + wc * 64 + u * 16 + l16];
#pragma unroll
    for (int t = 0; t < 4; ++t) acc[t][u] = {bv_, bv_, bv_, bv_};
  }

  for (int k0 = 0; k0 < H; k0 += 64) {
    __syncthreads();
#pragma unroll
    for (int i = 0; i < 4; ++i) {
      gll16(aptr[i] + k0, &As[(w * 256 + i * 64) * 8]);
      gll16(bptr[i] + k0, &Bs[(w * 256 + i * 64) * 8]);
    }
    __syncthreads();
#pragma unroll
    for (int kc = 0; kc < 2; ++kc) {
      bf16x8 af[4], bfr[4];
#pragma unroll
      for (int t = 0; t < 4; ++t) {
        int ra = wr * 64 + t * 16 + l16;
        af[t] = *(const bf16x8*)&As[ra * 64 + (((kc * 4 + quad) ^ (ra & 7)) * 8)];
        int rb = wc * 64 + t * 16 + l16;
        bfr[t] = *(const bf16x8*)&Bs[rb * 64 + (((kc * 4 + quad) ^ (rb & 7)) * 8)];
      }
#pragma unroll
      for (int t = 0; t < 4; ++t)
#pragma unroll
        for (int u = 0; u < 4; ++u)
          acc[t][u] = __builtin_amdgcn_mfma_f32_16x16x32_bf16(af[t], bfr[u], acc[t][u], 0, 0, 0);
    }
  }

  const int b = m0 >> 11;
  if (wsel <= 1) {
    // LDS-bounce transpose: per-wave 64x64 region of the dead staging pool.
    __syncthreads();                         // staging LDS now dead
    __bf16* Tr = smem + w * (64 * 64);
    const float scl = wsel == 0 ? 0.125f * L2E : 1.0f;
#pragma unroll
    for (int t = 0; t < 4; ++t)
#pragma unroll
      for (int u = 0; u < 4; ++u)
#pragma unroll
        for (int r = 0; r < 4; ++r) {
          int row = t * 16 + quad * 4 + r;       // s within quadrant
          int col = u * 16 + l16;                // d within head
          Tr[row * 64 + (((col >> 3) ^ (row & 7)) * 8 + (col & 7))] =
              (__bf16)(acc[t][u][r] * scl);
        }
    // lane reads its row (64 d contiguous) and stores 8x16B coalesced
    const int head = (n0 + wc * 64) >> 6;
    const int bh = b * NH + head;
    const int si = (m0 & (S - 1)) + wr * 64 + lane;
    __bf16* dst = (wsel == 0 ? Q : K) + ((size_t)bh * S + si) * DH;
#pragma unroll
    for (int c = 0; c < 8; ++c)
      *(bf16x8*)&dst[c * 8] =
          *(const bf16x8*)&Tr[lane * 64 + ((c ^ (lane & 7)) * 8)];
  } else {
#pragma unroll
    for (int u = 0; u < 4; ++u) {
      int n = n0 + wc * 64 + u * 16 + l16;
      int head = n >> 6, d = n & 63;
#pragma unroll
      for (int t = 0; t < 4; ++t) {
        int srow = m0 + wr * 64 + t * 16 + quad * 4;
        int si = srow & (S - 1);
        int bh = b * NH + head;
        bf16x4 o;
#pragma unroll
        for (int r = 0; r < 4; ++r) o[r] = (__bf16)acc[t][u][r];
        *(bf16x4*)&Vt[((size_t)bh * DH + d) * S + si] = o;
      }
    }
  }
}

// Flash attention (r5-exact structure): transposed scores, fixed-max softmax.
// grid (16, 32), 512 threads (8 waves), kv tiles of 128.
__global__ __launch_bounds__(512, 4) void attn_kernel(
    const __bf16* __restrict__ Q, const __bf16* __restrict__ K,
    const __bf16* __restrict__ Vt, const float* __restrict__ mask,
    float* __restrict__ out)
{
  __shared__ __bf16 Ks[128 * 64];     // [kv][d], 8 chunks/row, swizzled
  __shared__ __bf16 Vs[64 * 128];     // [d][kv], 16 chunks/row, swizzled
  __shared__ float  Ms[S];            // mask * log2e, staged once (8 KB)
  __shared__ __bf16 Pb[8][16][128];   // per-wave P[q][kv], XOR chunk swizzle

  const int tid = threadIdx.x, lane = tid & 63, w = tid >> 6;  // w: 0..7
  const int quad = lane >> 4, l16 = lane & 15;
  const int bh = blockIdx.y, b = bh >> 4, h = bh & 15;
  const int q0 = blockIdx.x * 128;

  const __bf16* Qb = Q + (size_t)bh * S * DH;    // [s][d]
  const __bf16* Kb = K + (size_t)bh * S * DH;    // [s][d]
  const __bf16* Vb = Vt + (size_t)bh * DH * S;   // [d][s]
  const float* mb = mask + (size_t)b * S;

  // stage mask once, pre-scaled by log2(e)
  {
    int idx = tid * 4;
    float4 mv = *(const float4*)&mb[idx];
    float4 sv = {mv.x * L2E, mv.y * L2E, mv.z * L2E, mv.w * L2E};
    *(float4*)&Ms[idx] = sv;
  }

  // Q B-fragments, now vectorized: Q[q][kc*32+quad*8 .. +8] contiguous
  const int q = q0 + w * 16 + l16;
  bf16x8 qf[2];
#pragma unroll
  for (int kc = 0; kc < 2; ++kc)
    qf[kc] = *(const bf16x8*)&Qb[(size_t)q * DH + kc * 32 + quad * 8];

  // ones A-fragment (row m=0) for the denominator MFMA
  bf16x8 ones_frag;
#pragma unroll
  for (int j = 0; j < 8; ++j) ones_frag[j] = (l16 == 0) ? (__bf16)1.0f : (__bf16)0.0f;

  const __bf16* kptr[2];
  const __bf16* vptr[2];
#pragma unroll
  for (int i = 0; i < 2; ++i) {
    int s = i * 512 + tid;
    {
      int row = s >> 3, col = s & 7, sc = col ^ (row & 7);
      kptr[i] = Kb + (size_t)row * DH + sc * 8;
    }
    {
      int row = s >> 4, col = s & 15, sc = col ^ (row & 15);
      vptr[i] = Vb + (size_t)row * S + sc * 8;
    }
  }

  f32x4 o[4] = {};
  f32x4 o4 = {};   // denominator (row 0 of ones-MFMA)

  for (int kv0 = 0; kv0 < S; kv0 += 128) {
    __syncthreads();
#pragma unroll
    for (int i = 0; i < 2; ++i) {
      gll16(kptr[i] + (size_t)kv0 * DH, &Ks[(i * 512 + w * 64) * 8]);
      gll16(vptr[i] + kv0, &Vs[(i * 512 + w * 64) * 8]);
    }
    __syncthreads();

    // scores S^T (log2 domain), C-init = mask*log2e; P=exp2 -> per-wave LDS
#pragma unroll
    for (int t = 0; t < 8; ++t) {
      int rk = t * 16 + l16;
      bf16x8 k0f = *(const bf16x8*)&Ks[rk * 64 + ((quad ^ (rk & 7)) * 8)];
      bf16x8 k1f = *(const bf16x8*)&Ks[rk * 64 + (((4 + quad) ^ (rk & 7)) * 8)];
      float4 m4 = *(const float4*)&Ms[kv0 + t * 16 + quad * 4];
      f32x4 z = {m4.x, m4.y, m4.z, m4.w};
      z = __builtin_amdgcn_mfma_f32_16x16x32_bf16(k0f, qf[0], z, 0, 0, 0);
      f32x4 sc = __builtin_amdgcn_mfma_f32_16x16x32_bf16(k1f, qf[1], z, 0, 0, 0);
      bf16x4 pk;
#pragma unroll
      for (int r = 0; r < 4; ++r) pk[r] = (__bf16)EXP2F(sc[r]);
      int col = t * 16 + quad * 4;
      *(bf16x4*)&Pb[w][l16][(((col >> 3) ^ l16) & 15) * 8 + (col & 7)] = pk;
    }

    // O^T += V^T P^T ; ones-row MFMA accumulates denominator into o4
#pragma unroll
    for (int tt = 0; tt < 4; ++tt) {
      bf16x8 pf = *(const bf16x8*)&Pb[w][l16][(((tt * 4 + quad) ^ l16) & 15) * 8];
#pragma unroll
      for (int u = 0; u < 4; ++u) {
        int d = u * 16 + l16;
        bf16x8 vf = *(const bf16x8*)&Vs[d * 128 + (((4 * tt + quad) ^ l16) * 8)];
        o[u] = __builtin_amdgcn_mfma_f32_16x16x32_bf16(vf, pf, o[u], 0, 0, 0);
      }
      o4 = __builtin_amdgcn_mfma_f32_16x16x32_bf16(ones_frag, pf, o4, 0, 0, 0);
    }
  }

  // denominator for q-col l16 sits on lane l16 (quad 0), reg 0
  float l_q = __shfl(o4[0], l16, 64);
  float invl = 1.0f / l_q;
#pragma unroll
  for (int u = 0; u < 4; ++u) {
    float4 st = {o[u][0] * invl, o[u][1] * invl, o[u][2] * invl, o[u][3] * invl};
    *(float4*)&out[((size_t)b * S + q) * H + h * DH + u * 16 + quad * 4] = st;
  }
}

extern "C" void kernel_launch(void* const* d_in, const int* in_sizes, int n_in,
                              void* d_out, int out_size, void* d_ws, size_t ws_size,
                              hipStream_t stream) {
  const float* X    = (const float*)d_in[0];
  const float* mask = (const float*)d_in[1];
  const float* Wq   = (const float*)d_in[2];
  const float* bq   = (const float*)d_in[3];
  const float* Wk   = (const float*)d_in[4];
  const float* bk   = (const float*)d_in[5];
  const float* Wv   = (const float*)d_in[6];
  const float* bv   = (const float*)d_in[7];
  float* out = (float*)d_out;

  const size_t per = (size_t)2 * NH * S * DH;   // 4M elems
  __bf16* Qws  = (__bf16*)d_ws;                 // 8MB  [bh][s][d]
  __bf16* Kws  = Qws + per;                     // 8MB  [bh][s][d]
  __bf16* Vtws = Kws + per;                     // 8MB  [bh][d][s]

  // GEMM-phase scratch inside d_out (16MB); attn overwrites all of d_out.
  __bf16* Xb = (__bf16*)d_out;                  // 8MB
  __bf16* Wt = Xb + per;                        // 3 x 2MB

  convert_kernel<<<2816, 256, 0, stream>>>(X, Wq, Wk, Wv, Xb, Wt);
  qkv_gemm_kernel<<<dim3(24, 32), 256, 0, stream>>>(Xb, Wt, bq, bk, bv,
                                                    Qws, Kws, Vtws);
  attn_kernel<<<dim3(16, 32), 512, 0, stream>>>(Qws, Kws, Vtws, mask, out);
}